// Round 2
// baseline (29285.999 us; speedup 1.0000x reference)
//
#include <hip/hip_runtime.h>

// LSTM: B=64, T=1024, D=512, H=512. Gate order i,f,g,o.
// Plan: phase A = xW GEMM (f16 MFMA, chunked over T into ws);
//       phase B = persistent scan kernel, 256 WGs = 4 row-groups(16 rows) x 64 unit-slices(8 units),
//                 Wr B-frags held in registers, h exchanged via LLC with flag sync.

#define B_  64
#define T_  1024
#define D_  512
#define H_  512
#define G4H 2048

typedef _Float16 half8 __attribute__((ext_vector_type(8)));
typedef _Float16 half4 __attribute__((ext_vector_type(4)));
typedef float    f32x4 __attribute__((ext_vector_type(4)));

// ---------------- init: zero flags, transpose-convert kernel -> WkT f16 [2048][512]
__global__ void init_kernel(const float* __restrict__ Wk, _Float16* __restrict__ WkT,
                            unsigned* __restrict__ arrive) {
    int idx = blockIdx.x * blockDim.x + threadIdx.x;
    if (idx < 4) arrive[idx] = 0;
    int total = D_ * G4H;
    int stride = gridDim.x * blockDim.x;
    for (int i = idx; i < total; i += stride) {
        int k = i >> 11;          // /2048
        int n = i & (G4H - 1);
        WkT[(size_t)n * D_ + k] = (_Float16)Wk[i];
    }
}

// ---------------- phase A: xw[t][b][col] = x[b][t][:] @ Wk[:][col]  (no bias; added in scan)
// tile: 64 t-rows x 64 cols, K=512 in BK=32 steps. 256 threads = 4 waves, wave w does rows 16w..16w+15.
__global__ __launch_bounds__(256) void gemm_xw(const float* __restrict__ x,
                                               const _Float16* __restrict__ WkT,
                                               float* __restrict__ xw,
                                               int tbase) {
    __shared__ _Float16 As[64][40];   // [t-row][k] pad 8
    __shared__ _Float16 Bst[64][40];  // [col][k]  pad 8 (transposed for B-frag reads)
    const int tid  = threadIdx.x;
    const int lane = tid & 63;
    const int wave = tid >> 6;
    const int l15  = lane & 15;
    const int quad = lane >> 4;
    const int b     = blockIdx.z;
    const int n0    = blockIdx.x * 64;
    const int tloc0 = blockIdx.y * 64;

    const float* xbase = x + ((size_t)b * T_ + (tbase + tloc0)) * D_;
    f32x4 acc[4];
#pragma unroll
    for (int i = 0; i < 4; ++i) acc[i] = (f32x4){0.f, 0.f, 0.f, 0.f};

    // A stage: row ai (0..63), 8 floats at ac*8  (256 thr x 8 = 2048 = 64x32  -- FIXED R1)
    const int ai = tid >> 2, ac = tid & 3;
    // B stage: col bn (0..63), 8 f16 at bq*8     (256 thr x 8 = 2048 = 64x32)
    const int bn = tid >> 2, bq = tid & 3;

    for (int kb = 0; kb < 16; ++kb) {
        __syncthreads();
        // stage A: x fp32 -> f16, 8 elements per thread
        const float* ap = xbase + (size_t)ai * D_ + kb * 32 + ac * 8;
        f32x4 av0 = *(const f32x4*)ap;
        f32x4 av1 = *(const f32x4*)(ap + 4);
        half8 ah = { (_Float16)av0.x, (_Float16)av0.y, (_Float16)av0.z, (_Float16)av0.w,
                     (_Float16)av1.x, (_Float16)av1.y, (_Float16)av1.z, (_Float16)av1.w };
        *(half8*)&As[ai][ac * 8] = ah;
        // stage B: WkT f16 (already [col][k])
        half8 bv = *(const half8*)(WkT + (size_t)(n0 + bn) * D_ + kb * 32 + bq * 8);
        *(half8*)&Bst[bn][bq * 8] = bv;
        __syncthreads();

        half8 afrag = *(const half8*)&As[16 * wave + l15][quad * 8];
#pragma unroll
        for (int nt = 0; nt < 4; ++nt) {
            half8 bfrag = *(const half8*)&Bst[nt * 16 + l15][quad * 8];
            acc[nt] = __builtin_amdgcn_mfma_f32_16x16x32_f16(afrag, bfrag, acc[nt], 0, 0, 0);
        }
    }
    // epilogue: C row = quad*4+r, col = l15 (per 16x16 tile)
#pragma unroll
    for (int nt = 0; nt < 4; ++nt)
#pragma unroll
        for (int r = 0; r < 4; ++r) {
            int tt  = tloc0 + 16 * wave + quad * 4 + r;
            int col = n0 + nt * 16 + l15;
            xw[((size_t)tt * B_ + b) * G4H + col] = acc[nt][r];
        }
}

// ---------------- phase B: persistent scan
// grid 256, block 128 (2 waves). WG w: group g=w&3 (rows g*16..+15), slice s=w>>2 (units s*8..+7).
// wave v owns 16 gate-cols: local col nl = v*16+l15, global col = (nl>>3)*512 + u0 + (nl&7).
__global__ __launch_bounds__(128) void lstm_scan(const float* __restrict__ xw,   // [ct][B][4H]
                                                 const float* __restrict__ Wr,   // [512][2048]
                                                 const float* __restrict__ bias, // [2048]
                                                 _Float16* __restrict__ hbuf,    // [2][B][H]
                                                 float* __restrict__ cio,        // [B][H]
                                                 unsigned* __restrict__ arrive,  // [4]
                                                 float* __restrict__ out,        // [B][H]
                                                 int t0, int t1) {
    const int w    = blockIdx.x;
    const int g    = w & 3;
    const int s    = w >> 2;
    const int u0   = s * 8;
    const int tid  = threadIdx.x;
    const int lane = tid & 63;
    const int wave = tid >> 6;
    const int l15  = lane & 15;
    const int quad = lane >> 4;

    // load Wr B-fragments into registers once (reused for all timesteps)
    half8 bfrag[16];
    {
        const int nl  = wave * 16 + l15;
        const int col = (nl >> 3) * H_ + u0 + (nl & 7);
#pragma unroll
        for (int kt = 0; kt < 16; ++kt) {
            half8 v;
#pragma unroll
            for (int j = 0; j < 8; ++j) {
                int k = kt * 32 + quad * 8 + j;
                v[j] = (_Float16)Wr[(size_t)k * G4H + col];
            }
            bfrag[kt] = v;
        }
    }

    // epilogue mapping: thread -> (row rho, unit jj)
    const int rho  = tid >> 3;
    const int jj   = tid & 7;
    const int brow = g * 16 + rho;
    const float bi = bias[0 * H_ + u0 + jj];
    const float bf = bias[1 * H_ + u0 + jj];
    const float bg = bias[2 * H_ + u0 + jj];
    const float bo = bias[3 * H_ + u0 + jj];
    float c = (t0 == 0) ? 0.0f : cio[(size_t)brow * H_ + u0 + jj];

    __shared__ float zS[16][33];

    for (int t = t0; t < t1; ++t) {
        // wait until all 64 WGs of this group published h_{t-1}
        const unsigned target = (unsigned)(64 * t);
        int guard = 0;
        while (__hip_atomic_load(&arrive[g], __ATOMIC_RELAXED, __HIP_MEMORY_SCOPE_AGENT) < target) {
            if (++guard > (1 << 20)) break;   // bailout: wrong output instead of hang
            __builtin_amdgcn_s_sleep(1);
        }
        __threadfence();  // acquire: make partners' h stores visible

        f32x4 acc = {0.f, 0.f, 0.f, 0.f};
        if (t > 0) {
            const _Float16* hb = hbuf + ((size_t)((t - 1) & 1) * B_ + g * 16) * H_;
#pragma unroll
            for (int kt = 0; kt < 16; ++kt) {
                half8 af = *(const half8*)(hb + (size_t)l15 * H_ + kt * 32 + quad * 8);
                acc = __builtin_amdgcn_mfma_f32_16x16x32_f16(af, bfrag[kt], acc, 0, 0, 0);
            }
        }
        // exchange z between the two waves
        {
            const int colb = wave * 16 + l15;
#pragma unroll
            for (int r = 0; r < 4; ++r) zS[quad * 4 + r][colb] = acc[r];
        }
        __syncthreads();

        const float* xwt = xw + ((size_t)(t - t0) * B_ + brow) * G4H;
        float zi = zS[rho][jj]      + xwt[0 * H_ + u0 + jj] + bi;
        float zf = zS[rho][8 + jj]  + xwt[1 * H_ + u0 + jj] + bf;
        float zg = zS[rho][16 + jj] + xwt[2 * H_ + u0 + jj] + bg;
        float zo = zS[rho][24 + jj] + xwt[3 * H_ + u0 + jj] + bo;

        float ig = 1.f / (1.f + __expf(-zi));
        float fg = 1.f / (1.f + __expf(-zf));
        float zgc = fminf(fmaxf(zg, -15.f), 15.f);
        float e2g = __expf(2.f * zgc);
        float gg = (e2g - 1.f) / (e2g + 1.f);
        float og = 1.f / (1.f + __expf(-zo));

        c = fg * c + ig * gg;
        float cc  = fminf(fmaxf(c, -15.f), 15.f);
        float e2c = __expf(2.f * cc);
        float th  = (e2c - 1.f) / (e2c + 1.f);
        float h   = og * th;

        hbuf[((size_t)(t & 1) * B_ + brow) * H_ + u0 + jj] = (_Float16)h;
        if (t == T_ - 1) out[(size_t)brow * H_ + u0 + jj] = h;

        __threadfence();          // release our h stores to agent scope
        __syncthreads();          // all threads' stores done before publish
        if (tid == 0)
            __hip_atomic_fetch_add(&arrive[g], 1u, __ATOMIC_RELEASE, __HIP_MEMORY_SCOPE_AGENT);
    }
    cio[(size_t)brow * H_ + u0 + jj] = c;  // persist c for next chunk (harmless on last)
}

// ---------------- launch
extern "C" void kernel_launch(void* const* d_in, const int* in_sizes, int n_in,
                              void* d_out, int out_size, void* d_ws, size_t ws_size,
                              hipStream_t stream) {
    const float* x    = (const float*)d_in[0];
    const float* Wk   = (const float*)d_in[1];
    const float* Wr   = (const float*)d_in[2];
    const float* bias = (const float*)d_in[3];
    float* out = (float*)d_out;

    char* ws = (char*)d_ws;
    unsigned* arrive = (unsigned*)ws;                           // 256 B
    _Float16* WkT    = (_Float16*)(ws + 256);                   // 2 MB
    _Float16* hbuf   = (_Float16*)(ws + 256 + 2097152);         // 128 KB
    float*    cio    = (float*)  (ws + 256 + 2097152 + 131072); // 128 KB
    const size_t fixed = 256 + 2097152 + 131072 + 131072;       // 2359552
    float*    xw     = (float*)(ws + fixed);

    size_t avail = (ws_size > fixed) ? ws_size - fixed : 0;
    int ct = 0;
    const int cands[5] = {1024, 512, 256, 128, 64};
    for (int i = 0; i < 5; ++i) {
        if ((size_t)cands[i] * (size_t)(B_ * G4H * 4) <= avail) { ct = cands[i]; break; }
    }
    if (ct == 0) {  // workspace too small: fail visibly but safely
        hipMemsetAsync(d_out, 0, (size_t)out_size * 4, stream);
        return;
    }

    init_kernel<<<512, 256, 0, stream>>>(Wk, WkT, arrive);
    for (int t0 = 0; t0 < T_; t0 += ct) {
        gemm_xw<<<dim3(32, ct / 64, B_), 256, 0, stream>>>(x, WkT, xw, t0);
        lstm_scan<<<256, 128, 0, stream>>>(xw, Wr, bias, hbuf, cio, arrive, out, t0, t0 + ct);
    }
}

// Round 3
// 6042.851 us; speedup vs baseline: 4.8464x; 4.8464x over previous
//
#include <hip/hip_runtime.h>

// LSTM: B=64, T=1024, D=512, H=512. Gate order i,f,g,o.
// Phase A: xW GEMM (f16 MFMA, chunked over T into ws, output f16).
// Phase B: persistent scan, 128 WGs = 4 row-groups(16 rows) x 32 unit-slices(16 units).
//   Wave v of each WG handles gate v. Wr B-frags in registers (64 VGPR/lane).
//   Cross-WG h exchange via MALL-coherent (agent-scope relaxed, sc0 sc1) accesses.
//   NO fences / NO RMW atomics in the loop: per-WG flag words + ballot poll.

#define B_  64
#define T_  1024
#define D_  512
#define H_  512
#define G4H 2048
#define NWG 128
#define FANIN 32

typedef _Float16 half8 __attribute__((ext_vector_type(8)));
typedef float    f32x4 __attribute__((ext_vector_type(4)));

// ---------------- init: zero flags, transpose-convert kernel -> WkT f16 [2048][512]
__global__ void init_kernel(const float* __restrict__ Wk, _Float16* __restrict__ WkT,
                            unsigned* __restrict__ flags) {
    int idx = blockIdx.x * blockDim.x + threadIdx.x;
    if (idx < NWG) flags[idx] = 0;
    int total = D_ * G4H;
    int stride = gridDim.x * blockDim.x;
    for (int i = idx; i < total; i += stride) {
        int k = i >> 11;          // /2048
        int n = i & (G4H - 1);
        WkT[(size_t)n * D_ + k] = (_Float16)Wk[i];
    }
}

// ---------------- phase A: xw[t][b][col] = x[b][t][:] @ Wk[:][col], stored f16
__global__ __launch_bounds__(256) void gemm_xw(const float* __restrict__ x,
                                               const _Float16* __restrict__ WkT,
                                               _Float16* __restrict__ xw,
                                               int tbase) {
    __shared__ _Float16 As[64][40];
    __shared__ _Float16 Bst[64][40];
    const int tid  = threadIdx.x;
    const int lane = tid & 63;
    const int wave = tid >> 6;
    const int l15  = lane & 15;
    const int quad = lane >> 4;
    const int b     = blockIdx.z;
    const int n0    = blockIdx.x * 64;
    const int tloc0 = blockIdx.y * 64;

    const float* xbase = x + ((size_t)b * T_ + (tbase + tloc0)) * D_;
    f32x4 acc[4];
#pragma unroll
    for (int i = 0; i < 4; ++i) acc[i] = (f32x4){0.f, 0.f, 0.f, 0.f};

    const int ai = tid >> 2, ac = tid & 3;   // A: row ai, 8 floats at ac*8
    const int bn = tid >> 2, bq = tid & 3;   // B: col bn, 8 f16 at bq*8

    for (int kb = 0; kb < 16; ++kb) {
        __syncthreads();
        const float* ap = xbase + (size_t)ai * D_ + kb * 32 + ac * 8;
        f32x4 av0 = *(const f32x4*)ap;
        f32x4 av1 = *(const f32x4*)(ap + 4);
        half8 ah = { (_Float16)av0.x, (_Float16)av0.y, (_Float16)av0.z, (_Float16)av0.w,
                     (_Float16)av1.x, (_Float16)av1.y, (_Float16)av1.z, (_Float16)av1.w };
        *(half8*)&As[ai][ac * 8] = ah;
        half8 bv = *(const half8*)(WkT + (size_t)(n0 + bn) * D_ + kb * 32 + bq * 8);
        *(half8*)&Bst[bn][bq * 8] = bv;
        __syncthreads();

        half8 afrag = *(const half8*)&As[16 * wave + l15][quad * 8];
#pragma unroll
        for (int nt = 0; nt < 4; ++nt) {
            half8 bfrag = *(const half8*)&Bst[nt * 16 + l15][quad * 8];
            acc[nt] = __builtin_amdgcn_mfma_f32_16x16x32_f16(afrag, bfrag, acc[nt], 0, 0, 0);
        }
    }
#pragma unroll
    for (int nt = 0; nt < 4; ++nt)
#pragma unroll
        for (int r = 0; r < 4; ++r) {
            int tt  = tloc0 + 16 * wave + quad * 4 + r;
            int col = n0 + nt * 16 + l15;
            xw[((size_t)tt * B_ + b) * G4H + col] = (_Float16)acc[nt][r];
        }
}

// ---------------- phase B: persistent scan
// 128 WGs x 256 thr. WG w: group g=w&3 (rows g*16..+15), slice s=w>>2 (units s*16..+15).
// Wave v = gate v, columns col = v*512 + u0 + l15.
__global__ __launch_bounds__(256) void lstm_scan(const _Float16* __restrict__ xw,  // [ct][B][4H] f16
                                                 const float* __restrict__ Wr,     // [512][2048]
                                                 const float* __restrict__ bias,   // [2048]
                                                 _Float16* __restrict__ hbuf,      // [2][B][H]
                                                 float* __restrict__ cio,          // [B][H]
                                                 unsigned* __restrict__ flags,     // [128]
                                                 float* __restrict__ out,          // [B][H]
                                                 int t0, int t1) {
    const int w    = blockIdx.x;
    const int g    = w & 3;
    const int s    = w >> 2;
    const int u0   = s * 16;
    const int tid  = threadIdx.x;
    const int lane = tid & 63;
    const int wave = tid >> 6;
    const int l15  = lane & 15;
    const int quad = lane >> 4;

    // B-frags in registers: wave v handles gate v, 16 columns.
    half8 bfrag[16];
    {
        const int col = wave * H_ + u0 + l15;
#pragma unroll
        for (int kt = 0; kt < 16; ++kt) {
            half8 v;
#pragma unroll
            for (int j = 0; j < 8; ++j)
                v[j] = (_Float16)Wr[(size_t)(kt * 32 + quad * 8 + j) * G4H + col];
            bfrag[kt] = v;
        }
    }

    const int rho  = tid >> 4;       // batch-row within group
    const int jj   = tid & 15;       // unit within slice
    const int brow = g * 16 + rho;
    const int unit = u0 + jj;
    const float bi = bias[unit];
    const float bf = bias[H_ + unit];
    const float bg = bias[2 * H_ + unit];
    const float bo = bias[3 * H_ + unit];
    float c = (t0 == 0) ? 0.0f : cio[(size_t)brow * H_ + unit];

    __shared__ float zS[16][80];   // row stride 80: 2-way max bank aliasing (free)

    for (int t = t0; t < t1; ++t) {
        // prefetch this step's xw (independent of h)
        const _Float16* xwt = xw + ((size_t)(t - t0) * B_ + brow) * G4H;
        float xi = (float)xwt[unit];
        float xf = (float)xwt[H_ + unit];
        float xg = (float)xwt[2 * H_ + unit];
        float xo = (float)xwt[3 * H_ + unit];

        // wave 0: one coalesced poll of all 32 partner flags
        if (wave == 0) {
            const unsigned target = (unsigned)t;
            bool ok = (lane >= FANIN);
            int guard = 0;
            while (true) {
                if (!ok) {
                    unsigned v = __hip_atomic_load(&flags[g + 4 * lane],
                                                   __ATOMIC_RELAXED, __HIP_MEMORY_SCOPE_AGENT);
                    ok = (v >= target);
                }
                if (__all(ok)) break;
                if (++guard > (1 << 20)) break;   // bailout: wrong output, not a hang
                __builtin_amdgcn_s_sleep(1);
            }
        }
        __syncthreads();

        f32x4 acc = {0.f, 0.f, 0.f, 0.f};
        if (t > 0) {
            // h_{t-1} A-frags: MALL-coherent 8B loads (bypass L1/L2)
            unsigned long long* hq = (unsigned long long*)
                (hbuf + ((size_t)((t - 1) & 1) * B_ + g * 16 + l15) * H_);
#pragma unroll
            for (int kt = 0; kt < 16; ++kt) {
                unsigned long long lo = __hip_atomic_load(&hq[kt * 8 + quad * 2],
                                            __ATOMIC_RELAXED, __HIP_MEMORY_SCOPE_AGENT);
                unsigned long long hi = __hip_atomic_load(&hq[kt * 8 + quad * 2 + 1],
                                            __ATOMIC_RELAXED, __HIP_MEMORY_SCOPE_AGENT);
                half8 af;
                ((unsigned long long*)&af)[0] = lo;
                ((unsigned long long*)&af)[1] = hi;
                acc = __builtin_amdgcn_mfma_f32_16x16x32_f16(af, bfrag[kt], acc, 0, 0, 0);
            }
        }
        // z exchange across the 4 gate-waves
#pragma unroll
        for (int r = 0; r < 4; ++r) zS[quad * 4 + r][wave * 16 + l15] = acc[r];
        __syncthreads();

        float zi = zS[rho][jj]      + xi + bi;
        float zf = zS[rho][16 + jj] + xf + bf;
        float zg = zS[rho][32 + jj] + xg + bg;
        float zo = zS[rho][48 + jj] + xo + bo;

        float ig = 1.f / (1.f + __expf(-zi));
        float fg = 1.f / (1.f + __expf(-zf));
        float zgc = fminf(fmaxf(zg, -15.f), 15.f);
        float e2g = __expf(2.f * zgc);
        float gg = (e2g - 1.f) / (e2g + 1.f);
        float og = 1.f / (1.f + __expf(-zo));

        c = fg * c + ig * gg;
        float cc  = fminf(fmaxf(c, -15.f), 15.f);
        float e2c = __expf(2.f * cc);
        float th  = (e2c - 1.f) / (e2c + 1.f);
        float h   = og * th;

        // pair adjacent units -> one dword MALL store per even thread
        float hp = __shfl_xor(h, 1);
        if ((tid & 1) == 0) {
            _Float16 h0 = (_Float16)h, h1 = (_Float16)hp;
            unsigned u = (unsigned)__builtin_bit_cast(unsigned short, h0) |
                         ((unsigned)__builtin_bit_cast(unsigned short, h1) << 16);
            __hip_atomic_store((unsigned*)(hbuf + ((size_t)(t & 1) * B_ + brow) * H_ + unit),
                               u, __ATOMIC_RELAXED, __HIP_MEMORY_SCOPE_AGENT);
        }
        if (t == T_ - 1) out[(size_t)brow * H_ + unit] = h;

        __syncthreads();   // drains vmcnt(0): all h stores are at the MALL
        if (tid == 0)
            __hip_atomic_store(&flags[w], (unsigned)(t + 1),
                               __ATOMIC_RELAXED, __HIP_MEMORY_SCOPE_AGENT);
    }
    cio[(size_t)brow * H_ + unit] = c;
}

// ---------------- launch
extern "C" void kernel_launch(void* const* d_in, const int* in_sizes, int n_in,
                              void* d_out, int out_size, void* d_ws, size_t ws_size,
                              hipStream_t stream) {
    const float* x    = (const float*)d_in[0];
    const float* Wk   = (const float*)d_in[1];
    const float* Wr   = (const float*)d_in[2];
    const float* bias = (const float*)d_in[3];
    float* out = (float*)d_out;

    char* ws = (char*)d_ws;
    unsigned* flags  = (unsigned*)ws;                             // 512 B (pad 1 KB)
    _Float16* WkT    = (_Float16*)(ws + 1024);                    // 2 MB
    _Float16* hbuf   = (_Float16*)(ws + 1024 + 2097152);          // 128 KB
    float*    cio    = (float*)  (ws + 1024 + 2097152 + 131072);  // 128 KB
    const size_t fixed = 1024 + 2097152 + 131072 + 131072;
    _Float16* xw     = (_Float16*)(ws + fixed);

    size_t avail = (ws_size > fixed) ? ws_size - fixed : 0;
    int ct = 0;
    const int cands[5] = {1024, 512, 256, 128, 64};
    for (int i = 0; i < 5; ++i) {
        if ((size_t)cands[i] * (size_t)(B_ * G4H * 2) <= avail) { ct = cands[i]; break; }
    }
    if (ct == 0) {
        hipMemsetAsync(d_out, 0, (size_t)out_size * 4, stream);
        return;
    }

    init_kernel<<<512, 256, 0, stream>>>(Wk, WkT, flags);
    for (int t0 = 0; t0 < T_; t0 += ct) {
        gemm_xw<<<dim3(32, ct / 64, B_), 256, 0, stream>>>(x, WkT, xw, t0);
        lstm_scan<<<NWG, 256, 0, stream>>>(xw, Wr, bias, hbuf, cio, flags, out, t0, t0 + ct);
    }
}

// Round 4
// 3364.062 us; speedup vs baseline: 8.7055x; 1.7963x over previous
//
#include <hip/hip_runtime.h>

// LSTM: B=64, T=1024, D=512, H=512. Gate order i,f,g,o.
// Phase A: xW GEMM (f16 MFMA, bias folded in, f16 output).
// Phase B: persistent scan, 64 WGs = 4 row-groups(16 rows) x 16 slices(32 units).
//   Tag-in-data publish: h stored as (f16 | epoch<<16) dwords, consumers poll data
//   directly (no flags, no fences, no store-drain barrier). Triple-buffered.

#define B_  64
#define T_  1024
#define D_  512
#define H_  512
#define G4H 2048

typedef _Float16 half8 __attribute__((ext_vector_type(8)));
typedef float    f32x4 __attribute__((ext_vector_type(4)));
typedef unsigned long long ull;

static __device__ __forceinline__ float sigm(float x) { return 1.f / (1.f + __expf(-x)); }
static __device__ __forceinline__ float tanh_(float x) {
    float xc = fminf(fmaxf(x, -15.f), 15.f);
    float e  = __expf(2.f * xc);
    return (e - 1.f) / (e + 1.f);
}
static __device__ __forceinline__ float lo16f(unsigned u) {
    return (float)__builtin_bit_cast(_Float16, (unsigned short)(u & 0xffffu));
}
static __device__ __forceinline__ float hi16f(unsigned u) {
    return (float)__builtin_bit_cast(_Float16, (unsigned short)(u >> 16));
}

// ---------------- init: transpose-convert kernel -> WkT f16 [2048][512]
__global__ void init_kernel(const float* __restrict__ Wk, _Float16* __restrict__ WkT) {
    int idx = blockIdx.x * blockDim.x + threadIdx.x;
    int total = D_ * G4H;
    int stride = gridDim.x * blockDim.x;
    for (int i = idx; i < total; i += stride) {
        int k = i >> 11;
        int n = i & (G4H - 1);
        WkT[(size_t)n * D_ + k] = (_Float16)Wk[i];
    }
}

// ---------------- phase A: xw[t][b][col] = x[b][t][:] @ Wk[:][col] + bias[col], f16
__global__ __launch_bounds__(256) void gemm_xw(const float* __restrict__ x,
                                               const _Float16* __restrict__ WkT,
                                               const float* __restrict__ bias,
                                               _Float16* __restrict__ xw,
                                               int tbase) {
    __shared__ _Float16 As[64][40];
    __shared__ _Float16 Bst[64][40];
    const int tid  = threadIdx.x;
    const int lane = tid & 63;
    const int wave = tid >> 6;
    const int l15  = lane & 15;
    const int quad = lane >> 4;
    const int b     = blockIdx.z;
    const int n0    = blockIdx.x * 64;
    const int tloc0 = blockIdx.y * 64;

    const float* xbase = x + ((size_t)b * T_ + (tbase + tloc0)) * D_;
    f32x4 acc[4];
#pragma unroll
    for (int i = 0; i < 4; ++i) acc[i] = (f32x4){0.f, 0.f, 0.f, 0.f};

    const int ai = tid >> 2, ac = tid & 3;
    const int bn = tid >> 2, bq = tid & 3;

    for (int kb = 0; kb < 16; ++kb) {
        __syncthreads();
        const float* ap = xbase + (size_t)ai * D_ + kb * 32 + ac * 8;
        f32x4 av0 = *(const f32x4*)ap;
        f32x4 av1 = *(const f32x4*)(ap + 4);
        half8 ah = { (_Float16)av0.x, (_Float16)av0.y, (_Float16)av0.z, (_Float16)av0.w,
                     (_Float16)av1.x, (_Float16)av1.y, (_Float16)av1.z, (_Float16)av1.w };
        *(half8*)&As[ai][ac * 8] = ah;
        half8 bv = *(const half8*)(WkT + (size_t)(n0 + bn) * D_ + kb * 32 + bq * 8);
        *(half8*)&Bst[bn][bq * 8] = bv;
        __syncthreads();

        half8 afrag = *(const half8*)&As[16 * wave + l15][quad * 8];
#pragma unroll
        for (int nt = 0; nt < 4; ++nt) {
            half8 bfrag = *(const half8*)&Bst[nt * 16 + l15][quad * 8];
            acc[nt] = __builtin_amdgcn_mfma_f32_16x16x32_f16(afrag, bfrag, acc[nt], 0, 0, 0);
        }
    }
#pragma unroll
    for (int nt = 0; nt < 4; ++nt)
#pragma unroll
        for (int r = 0; r < 4; ++r) {
            int tt  = tloc0 + 16 * wave + quad * 4 + r;
            int col = n0 + nt * 16 + l15;
            xw[((size_t)tt * B_ + b) * G4H + col] = (_Float16)(acc[nt][r] + bias[col]);
        }
}

// ---------------- phase B: persistent scan, tag-in-data protocol
// 64 WGs x 256 thr. WG w: group g=w&3 (rows g*16..+15), slice s=w>>2 (units s*32..+31).
// Wave v = gate v, 2 column tiles of 16 (cols v*512 + u0 + 0..31).
// hbuf: 3 slots x [64][512] tagged dwords (lo16 = h f16, hi16 = step+1).
__global__ __launch_bounds__(256, 1) void lstm_scan(const _Float16* __restrict__ xw,
                                                    const float* __restrict__ Wr,
                                                    unsigned* __restrict__ hbuf,
                                                    float* __restrict__ cio,
                                                    float* __restrict__ out,
                                                    int t0, int t1) {
    const int w    = blockIdx.x;
    const int g    = w & 3;
    const int s    = w >> 2;
    const int u0   = s * 32;
    const int tid  = threadIdx.x;
    const int lane = tid & 63;
    const int wave = tid >> 6;
    const int l15  = lane & 15;
    const int quad = lane >> 4;

    // B-frags in registers: wave v = gate v, col tiles ct=0,1. 128 VGPRs.
    half8 bfrag[2][16];
#pragma unroll
    for (int ct = 0; ct < 2; ++ct) {
        const int col = wave * H_ + u0 + ct * 16 + l15;
#pragma unroll
        for (int kt = 0; kt < 16; ++kt) {
            half8 v;
#pragma unroll
            for (int j = 0; j < 8; ++j)
                v[j] = (_Float16)Wr[(size_t)(kt * 32 + quad * 8 + j) * G4H + col];
            bfrag[ct][kt] = v;
        }
    }

    const int rho  = tid >> 4;        // batch-row in group
    const int jj   = tid & 15;        // unit-pair in slice
    const int brow = g * 16 + rho;
    const int un0  = u0 + 2 * jj;     // this thread's two units
    float c0 = 0.f, c1 = 0.f;
    if (t0 != 0) {
        c0 = cio[(size_t)brow * H_ + un0];
        c1 = cio[(size_t)brow * H_ + un0 + 1];
    }

    __shared__ _Float16 hS[16][520];      // group h tile, pad 8 f16
    __shared__ float    zS[16][4][34];    // z exchange

    const size_t slotSz = (size_t)B_ * H_;   // dwords per slot

    for (int t = t0; t < t1; ++t) {
        // prefetch xw: 4 tagged... plain f16-pair dwords, one per gate
        const unsigned* xwd = (const unsigned*)(xw + ((size_t)(t - t0) * B_ + brow) * G4H);
        const int dbase = (u0 >> 1) + jj;
        unsigned xwi = xwd[0 * 256 + dbase];
        unsigned xwf = xwd[1 * 256 + dbase];
        unsigned xwg = xwd[2 * 256 + dbase];
        unsigned xwo = xwd[3 * 256 + dbase];

        if (t > 0) {
            // poll tagged h data directly: thread covers units 2*tid,2*tid+1 for all 16 rows
            const ull* src = (const ull*)(hbuf + (size_t)((t - 1) % 3) * slotSz)
                             + (size_t)(g * 16) * 256 + tid;
            const unsigned tgt = (unsigned)(t & 0xffff);
            const ull expect = ((ull)tgt << 16) | ((ull)tgt << 48);
            ull v[16];
            int guard = 0;
            while (true) {
                ull diff = 0;
#pragma unroll
                for (int k = 0; k < 16; ++k)
                    v[k] = __hip_atomic_load(src + (size_t)k * 256,
                                             __ATOMIC_RELAXED, __HIP_MEMORY_SCOPE_AGENT);
#pragma unroll
                for (int k = 0; k < 16; ++k)
                    diff |= (v[k] ^ expect) & 0xffff0000ffff0000ull;
                if (diff == 0) break;
                if (++guard > (1 << 14)) break;   // bailout: visible failure, not a hang
            }
            // strip tags, pack 2 f16 -> dword, stage to LDS
#pragma unroll
            for (int k = 0; k < 16; ++k) {
                unsigned p = (unsigned)(v[k] & 0xffffu) | (((unsigned)(v[k] >> 32)) << 16);
                *(unsigned*)&hS[k][2 * tid] = p;
            }
        }
        __syncthreads();   // BARRIER1: hS staged (also protects hS vs prev-step readers)

        f32x4 a0 = {0.f,0.f,0.f,0.f}, a1 = a0, b0 = a0, b1 = a0;
        if (t > 0) {
#pragma unroll
            for (int kt = 0; kt < 16; kt += 2) {
                half8 af0 = *(const half8*)&hS[l15][kt * 32 + quad * 8];
                half8 af1 = *(const half8*)&hS[l15][(kt + 1) * 32 + quad * 8];
                a0 = __builtin_amdgcn_mfma_f32_16x16x32_f16(af0, bfrag[0][kt],     a0, 0, 0, 0);
                a1 = __builtin_amdgcn_mfma_f32_16x16x32_f16(af0, bfrag[1][kt],     a1, 0, 0, 0);
                b0 = __builtin_amdgcn_mfma_f32_16x16x32_f16(af1, bfrag[0][kt + 1], b0, 0, 0, 0);
                b1 = __builtin_amdgcn_mfma_f32_16x16x32_f16(af1, bfrag[1][kt + 1], b1, 0, 0, 0);
            }
        }
        f32x4 z0 = a0 + b0, z1 = a1 + b1;
#pragma unroll
        for (int r = 0; r < 4; ++r) {
            zS[quad * 4 + r][wave][l15]      = z0[r];
            zS[quad * 4 + r][wave][16 + l15] = z1[r];
        }
        __syncthreads();   // BARRIER2: zS ready

        float zi0 = zS[rho][0][2*jj] + lo16f(xwi), zi1 = zS[rho][0][2*jj+1] + hi16f(xwi);
        float zf0 = zS[rho][1][2*jj] + lo16f(xwf), zf1 = zS[rho][1][2*jj+1] + hi16f(xwf);
        float zg0 = zS[rho][2][2*jj] + lo16f(xwg), zg1 = zS[rho][2][2*jj+1] + hi16f(xwg);
        float zo0 = zS[rho][3][2*jj] + lo16f(xwo), zo1 = zS[rho][3][2*jj+1] + hi16f(xwo);

        c0 = sigm(zf0) * c0 + sigm(zi0) * tanh_(zg0);
        c1 = sigm(zf1) * c1 + sigm(zi1) * tanh_(zg1);
        float h0 = sigm(zo0) * tanh_(c0);
        float h1 = sigm(zo1) * tanh_(c1);

        // tagged publish: one 8B relaxed agent store, no drain, no flag
        const unsigned tagw = ((unsigned)((t + 1) & 0xffff)) << 16;
        unsigned d0 = (unsigned)__builtin_bit_cast(unsigned short, (_Float16)h0) | tagw;
        unsigned d1 = (unsigned)__builtin_bit_cast(unsigned short, (_Float16)h1) | tagw;
        ull wv = (ull)d0 | ((ull)d1 << 32);
        __hip_atomic_store((ull*)(hbuf + (size_t)(t % 3) * slotSz) + (size_t)brow * 256 + (un0 >> 1),
                           wv, __ATOMIC_RELAXED, __HIP_MEMORY_SCOPE_AGENT);

        if (t == T_ - 1) {
            out[(size_t)brow * H_ + un0]     = h0;
            out[(size_t)brow * H_ + un0 + 1] = h1;
        }
    }
    cio[(size_t)brow * H_ + un0]     = c0;
    cio[(size_t)brow * H_ + un0 + 1] = c1;
}

// ---------------- launch
extern "C" void kernel_launch(void* const* d_in, const int* in_sizes, int n_in,
                              void* d_out, int out_size, void* d_ws, size_t ws_size,
                              hipStream_t stream) {
    const float* x    = (const float*)d_in[0];
    const float* Wk   = (const float*)d_in[1];
    const float* Wr   = (const float*)d_in[2];
    const float* bias = (const float*)d_in[3];
    float* out = (float*)d_out;

    char* ws = (char*)d_ws;
    _Float16* WkT   = (_Float16*)(ws + 1024);                       // 2 MB
    unsigned* hbuf  = (unsigned*)(ws + 1024 + 2097152);             // 384 KB (3 slots)
    float*    cio   = (float*)  (ws + 1024 + 2097152 + 393216);     // 128 KB
    const size_t fixed = 1024 + 2097152 + 393216 + 131072;
    _Float16* xw    = (_Float16*)(ws + fixed);

    size_t avail = (ws_size > fixed) ? ws_size - fixed : 0;
    int ct = 0;
    const int cands[5] = {1024, 512, 256, 128, 64};
    for (int i = 0; i < 5; ++i) {
        if ((size_t)cands[i] * (size_t)(B_ * G4H * 2) <= avail) { ct = cands[i]; break; }
    }
    if (ct == 0) {
        hipMemsetAsync(d_out, 0, (size_t)out_size * 4, stream);
        return;
    }

    init_kernel<<<512, 256, 0, stream>>>(Wk, WkT);
    for (int t0 = 0; t0 < T_; t0 += ct) {
        gemm_xw<<<dim3(32, ct / 64, B_), 256, 0, stream>>>(x, WkT, bias, xw, t0);
        lstm_scan<<<64, 256, 0, stream>>>(xw, Wr, hbuf, cio, out, t0, t0 + ct);
    }
}